// Round 1
// baseline (57657.715 us; speedup 1.0000x reference)
//
#include <hip/hip_runtime.h>

typedef unsigned int uint32;
typedef unsigned short uint16;

#define NSTEP 32768

// ---------------- helpers ----------------
__device__ __forceinline__ float rcp_(float x) {
#if __has_builtin(__builtin_amdgcn_rcpf)
  return __builtin_amdgcn_rcpf(x);
#else
  return 1.0f / x;
#endif
}
__device__ __forceinline__ float sigm_(float x) { return rcp_(1.0f + __expf(-x)); }
__device__ __forceinline__ float tanh_(float x) { return 1.0f - 2.0f * rcp_(1.0f + __expf(2.0f * x)); }

__device__ __forceinline__ float fdot2_(uint32 a, uint32 b, float c) {
#if __has_builtin(__builtin_amdgcn_fdot2)
  typedef _Float16 h2_t __attribute__((ext_vector_type(2)));
  return __builtin_amdgcn_fdot2(__builtin_bit_cast(h2_t, a), __builtin_bit_cast(h2_t, b), c, false);
#else
  float r;
  asm("v_dot2_f32_f16 %0, %1, %2, %3" : "=v"(r) : "v"(a), "v"(b), "v"(c));
  return r;
#endif
}
__device__ __forceinline__ uint16 f2h_(float x) { return __builtin_bit_cast(uint16, (_Float16)x); }

__device__ __forceinline__ uint32 aload_(uint32* p) {
  return __hip_atomic_load(p, __ATOMIC_RELAXED, __HIP_MEMORY_SCOPE_AGENT);
}
__device__ __forceinline__ void astore_(uint32* p, uint32 v) {
  __hip_atomic_store(p, v, __ATOMIC_RELAXED, __HIP_MEMORY_SCOPE_AGENT);
}

// ---------------- prep: fp16-pack LSTM weights + zero flags ----------------
__global__ __launch_bounds__(64) void prep_kernel(const float* __restrict__ Wih,
                                                  const float* __restrict__ Whh,
                                                  uint32* __restrict__ wih16,
                                                  uint32* __restrict__ whh16,
                                                  uint32* __restrict__ flags) {
  int rg = blockIdx.x;   // 0..3071 (1536 ih rows, 1536 hh rows)
  int d = threadIdx.x;   // 0..63
  const float* src = (rg < 1536) ? Wih : Whh;
  uint32* dst = (rg < 1536) ? wih16 : whh16;
  int row = (rg < 1536) ? rg : rg - 1536;
  float a = src[row * 128 + 2 * d];
  float b = src[row * 128 + 2 * d + 1];
  dst[row * 64 + d] = (uint32)f2h_(a) | ((uint32)f2h_(b) << 16);
  if (rg == 0 && d < 4) flags[d] = 0;
}

// ---------------- K/V projection (incl. pf row 0) ----------------
// K/V rows s: s==0 -> e = 1e-5*pf[b>>2]; s>=1 -> e = W_emb @ src[b>>2][s-1] + b_emb
// then k = Wk@e+bk, v = Wv@e+bv.  9 tiles of 57 rows = 513 exactly.
__global__ __launch_bounds__(256) void kv_proj_kernel(
    const float* __restrict__ src, const float* __restrict__ pf,
    const float* __restrict__ Wemb, const float* __restrict__ bemb,
    const float* __restrict__ Wk, const float* __restrict__ bk,
    const float* __restrict__ Wv, const float* __restrict__ bv,
    float* __restrict__ K, float* __restrict__ V, int in_d) {
  int b = blockIdx.y;
  int s0 = blockIdx.x * 57;
  int tid = threadIdx.x;
  int bsrc = b >> 2;  // jnp.repeat(..., 4, axis=0)
  __shared__ __align__(16) float e_tile[57][128];
  __shared__ __align__(16) float s_tile[57][60];
  int nsrc = 57 * in_d;
  for (int idx = tid; idx < nsrc; idx += 256) {
    int r = idx / in_d, i = idx - r * in_d;
    int s = s0 + r;
    s_tile[r][i] = (s >= 1) ? src[((size_t)bsrc * 512 + (s - 1)) * in_d + i] : 0.0f;
  }
  __syncthreads();
  int j = tid & 127, half = tid >> 7;
  int r0 = half ? 28 : 0;   // halves cover rows 0-28 / 28-56 (row 28 duplicated, identical value)
  {
    float acc[29];
    float bb = bemb[j];
#pragma unroll
    for (int r = 0; r < 29; ++r) acc[r] = bb;
    for (int i = 0; i < in_d; ++i) {
      float w = Wemb[j * in_d + i];
#pragma unroll
      for (int r = 0; r < 29; ++r) acc[r] += w * s_tile[r0 + r][i];
    }
#pragma unroll
    for (int r = 0; r < 29; ++r) {
      int s = s0 + r0 + r;
      e_tile[r0 + r][j] = (s == 0) ? (1e-5f * pf[(size_t)bsrc * 128 + j]) : acc[r];
    }
  }
  __syncthreads();
  {
    float acck[29], accv[29];
    float bkj = bk[j], bvj = bv[j];
#pragma unroll
    for (int r = 0; r < 29; ++r) { acck[r] = bkj; accv[r] = bvj; }
    for (int i = 0; i < 128; i += 4) {
      float4 wk = *(const float4*)&Wk[j * 128 + i];
      float4 wv = *(const float4*)&Wv[j * 128 + i];
#pragma unroll
      for (int r = 0; r < 29; ++r) {
        float4 e4 = *(const float4*)&e_tile[r0 + r][i];
        acck[r] += wk.x * e4.x + wk.y * e4.y + wk.z * e4.z + wk.w * e4.w;
        accv[r] += wv.x * e4.x + wv.y * e4.y + wv.z * e4.z + wv.w * e4.w;
      }
    }
#pragma unroll
    for (int r = 0; r < 29; ++r) {
      int s = s0 + r0 + r;
      K[((size_t)b * 513 + s) * 128 + j] = acck[r];
      V[((size_t)b * 513 + s) * 128 + j] = accv[r];
    }
  }
}

// ---------------- fused flash attention (fp32), q projected on the fly ----------------
__global__ __launch_bounds__(256) void attn_kernel(
    const float* __restrict__ lst,
    const float* __restrict__ Wemb, const float* __restrict__ bemb,
    const float* __restrict__ Wq, const float* __restrict__ bq,
    const float* __restrict__ Kg, const float* __restrict__ Vg,
    float* __restrict__ feat, int in_d) {
  int b = blockIdx.y, qt = blockIdx.x;
  int tid = threadIdx.x;
  __shared__ __align__(16) float q_tile[64][132];
  __shared__ __align__(16) float k_tile[60][132];
  __shared__ __align__(16) float v_tile[60][132];
  __shared__ __align__(16) float p_tile[64][60];
  // Phase A: stage listener rows into p_tile
  int nsrc = 64 * in_d;
  for (int idx = tid; idx < nsrc; idx += 256) {
    int r = idx / in_d, i = idx - r * in_d;
    p_tile[r][i] = lst[((size_t)b * 512 + qt * 64 + r) * in_d + i];
  }
  __syncthreads();
  int j = tid & 127, half = tid >> 7;
  int r0 = half * 32;
  {  // embed -> e (stored in k_tile)
    float acc[32];
    float bb = bemb[j];
#pragma unroll
    for (int r = 0; r < 32; ++r) acc[r] = bb;
    for (int i = 0; i < in_d; ++i) {
      float w = Wemb[j * in_d + i];
#pragma unroll
      for (int r = 0; r < 32; ++r) acc[r] += w * p_tile[r0 + r][i];
    }
#pragma unroll
    for (int r = 0; r < 32; ++r) k_tile[r0 + r][j] = acc[r];
  }
  __syncthreads();
  {  // q = Wq@e + bq
    float acc[32];
    float bb = bq[j];
#pragma unroll
    for (int r = 0; r < 32; ++r) acc[r] = bb;
    for (int i = 0; i < 128; i += 4) {
      float4 w4 = *(const float4*)&Wq[j * 128 + i];
#pragma unroll
      for (int r = 0; r < 32; ++r) {
        float4 e4 = *(const float4*)&k_tile[r0 + r][i];
        acc[r] += w4.x * e4.x + w4.y * e4.y + w4.z * e4.z + w4.w * e4.w;
      }
    }
#pragma unroll
    for (int r = 0; r < 32; ++r) q_tile[r0 + r][j] = acc[r];
  }
  // Phase B: flash loop, 9 tiles of 57 kv rows
  int r = tid >> 2, c4 = tid & 3;
  float m = -1e30f, l = 0.0f;
  float o[8][4];
#pragma unroll
  for (int kk = 0; kk < 8; ++kk)
#pragma unroll
    for (int x = 0; x < 4; ++x) o[kk][x] = 0.0f;
  const float SCALE = 0.08838834764831845f;  // 1/sqrt(128)
  for (int kt = 0; kt < 9; ++kt) {
    __syncthreads();
    for (int idx = tid; idx < 57 * 32; idx += 256) {
      int rr = idx >> 5, cc = idx & 31;
      *(float4*)&k_tile[rr][cc * 4] = *(const float4*)&Kg[((size_t)b * 513 + kt * 57 + rr) * 128 + cc * 4];
      *(float4*)&v_tile[rr][cc * 4] = *(const float4*)&Vg[((size_t)b * 513 + kt * 57 + rr) * 128 + cc * 4];
    }
    __syncthreads();
    float s[15];
#pragma unroll
    for (int jj = 0; jj < 15; ++jj) s[jj] = 0.0f;
    for (int i = 0; i < 128; i += 4) {
      float4 q4 = *(const float4*)&q_tile[r][i];
#pragma unroll
      for (int jj = 0; jj < 15; ++jj) {
        float4 k4 = *(const float4*)&k_tile[c4 + jj * 4][i];
        s[jj] += q4.x * k4.x + q4.y * k4.y + q4.z * k4.z + q4.w * k4.w;
      }
    }
    float tmax = -1e30f;
#pragma unroll
    for (int jj = 0; jj < 15; ++jj) {
      int jcol = c4 + jj * 4;
      s[jj] = (jcol < 57) ? s[jj] * SCALE : -1e30f;
      tmax = fmaxf(tmax, s[jj]);
    }
    tmax = fmaxf(tmax, __shfl_xor(tmax, 1));
    tmax = fmaxf(tmax, __shfl_xor(tmax, 2));
    float mnew = fmaxf(m, tmax);
    float corr = __expf(m - mnew);
    float psum = 0.0f;
#pragma unroll
    for (int jj = 0; jj < 15; ++jj) {
      float p = __expf(s[jj] - mnew);
      psum += p;
      p_tile[r][c4 + jj * 4] = p;  // row width 60: cols 57..59 are pad
    }
    psum += __shfl_xor(psum, 1);
    psum += __shfl_xor(psum, 2);
    l = l * corr + psum;
    m = mnew;
#pragma unroll
    for (int kk = 0; kk < 8; ++kk)
#pragma unroll
      for (int x = 0; x < 4; ++x) o[kk][x] *= corr;
    __syncthreads();
    for (int jcol = 0; jcol < 57; ++jcol) {
      float p = p_tile[r][jcol];
#pragma unroll
      for (int kk = 0; kk < 8; ++kk) {
        float4 v4 = *(const float4*)&v_tile[jcol][c4 * 4 + kk * 16];
        o[kk][0] += p * v4.x; o[kk][1] += p * v4.y; o[kk][2] += p * v4.z; o[kk][3] += p * v4.w;
      }
    }
  }
  float rl = 1.0f / l;
#pragma unroll
  for (int kk = 0; kk < 8; ++kk) {
    float4 st;
    st.x = o[kk][0] * rl; st.y = o[kk][1] * rl; st.z = o[kk][2] * rl; st.w = o[kk][3] * rl;
    *(float4*)&feat[((size_t)b * 512 + qt * 64 + r) * 128 + c4 * 4 + kk * 16] = st;
  }
}

// ---------------- fusion: enc = [fe,fd]@Wfus.T+b, written time-major as fp16 ----------------
__global__ __launch_bounds__(256) void fuse_kernel(
    const float* __restrict__ fe, const float* __restrict__ fd,
    const float* __restrict__ Wfus, const float* __restrict__ bfus,
    uint16* __restrict__ flat16) {
  int b = blockIdx.y, tt = blockIdx.x;
  int tid = threadIdx.x;
  __shared__ __align__(16) float f_tile[64][260];
  for (int idx = tid; idx < 64 * 32; idx += 256) {
    int r = idx >> 5, c = idx & 31;
    *(float4*)&f_tile[r][c * 4] = *(const float4*)&fe[((size_t)b * 512 + tt * 64 + r) * 128 + c * 4];
    *(float4*)&f_tile[r][128 + c * 4] = *(const float4*)&fd[((size_t)b * 512 + tt * 64 + r) * 128 + c * 4];
  }
  __syncthreads();
  int j = tid & 127, half = tid >> 7;
  int r0 = half * 32;
  float acc[32];
  float bb = bfus[j];
#pragma unroll
  for (int r = 0; r < 32; ++r) acc[r] = bb;
  for (int i = 0; i < 256; i += 4) {
    float4 w4 = *(const float4*)&Wfus[j * 256 + i];
#pragma unroll
    for (int r = 0; r < 32; ++r) {
      float4 e4 = *(const float4*)&f_tile[r0 + r][i];
      acc[r] += w4.x * e4.x + w4.y * e4.y + w4.z * e4.z + w4.w * e4.w;
    }
  }
#pragma unroll
  for (int r = 0; r < 32; ++r) {
    int t = tt * 64 + r0 + r;
    flat16[((size_t)t * 64 + b) * 128 + j] = f2h_(acc[r]);  // flat row = t*64+b
  }
}

// ---------------- persistent pipelined LSTM: 3 blocks = 3 layers ----------------
// Thread j owns gate row j of W_ih[z] and W_hh[z] (fp16x2 in 128 VGPRs).
// Stage z publishes h (packed fp16 pairs) to write-once per-step slots; stage z+1
// consumes with a cached watermark + 1-step prefetch. Forward-only deps: no deadlock.
__global__ __launch_bounds__(512) void lstm_kernel(
    const uint32* __restrict__ wih16, const uint32* __restrict__ whh16,
    const float* __restrict__ bih, const float* __restrict__ bhh,
    const uint32* __restrict__ flat16,
    uint32* hand32, uint32* flags,
    float* __restrict__ outs64) {
  const int z = blockIdx.x;
  const int j = threadIdx.x;
  __shared__ __align__(16) uint32 x16[64];
  __shared__ __align__(16) uint32 h16[64];
  __shared__ __align__(16) float act[512];
  uint32 wih[64], whh[64];
  {
    const uint32* p = &wih16[((size_t)z * 512 + j) * 64];
#pragma unroll
    for (int k = 0; k < 16; ++k) {
      uint4 t4 = *(const uint4*)&p[4 * k];
      wih[4 * k] = t4.x; wih[4 * k + 1] = t4.y; wih[4 * k + 2] = t4.z; wih[4 * k + 3] = t4.w;
    }
    const uint32* q = &whh16[((size_t)z * 512 + j) * 64];
#pragma unroll
    for (int k = 0; k < 16; ++k) {
      uint4 t4 = *(const uint4*)&q[4 * k];
      whh[4 * k] = t4.x; whh[4 * k + 1] = t4.y; whh[4 * k + 2] = t4.z; whh[4 * k + 3] = t4.w;
    }
  }
  float bc = bih[(size_t)z * 512 + j] + bhh[(size_t)z * 512 + j];
  float c0 = 0.0f, c1 = 0.0f;  // thread j<64 owns hidden units 2j, 2j+1
  if (j < 64) { x16[j] = 0; h16[j] = 0; }
  __syncthreads();
  const size_t hstride = (size_t)NSTEP * 64;
  uint32* flagA = (z > 0) ? &flags[z - 1] : (uint32*)0;
  uint32 FA = 0;
  bool prefv = false;
  uint32 xpref = 0, xv = 0;
  for (int t = 0; t < NSTEP; ++t) {
    // ---- acquire x for this step (wave0 only), prefetch next ----
    if (j < 64) {
      if (z == 0) {
        xv = prefv ? xpref : flat16[(size_t)t * 64 + j];
        xpref = flat16[(size_t)(t + 1) * 64 + j];  // t=32767 reads pad inside ws region; never consumed
        prefv = true;
      } else {
        if (!prefv) {
          while (FA <= (uint32)t) FA = aload_(flagA);
          xv = aload_(&hand32[(size_t)(z - 1) * hstride + (size_t)t * 64 + j]);
        } else {
          xv = xpref;
        }
        if (FA <= (uint32)(t + 1)) FA = aload_(flagA);
        prefv = FA > (uint32)(t + 1);
        if (prefv) xpref = aload_(&hand32[(size_t)(z - 1) * hstride + (size_t)(t + 1) * 64 + j]);
      }
    }
    // ---- hh dot (h16 stable since B3 of previous step) ----
    float ah = 0.0f;
#pragma unroll
    for (int k = 0; k < 16; ++k) {
      uint4 hv = *(const uint4*)&h16[4 * k];
      ah = fdot2_(whh[4 * k + 0], hv.x, ah);
      ah = fdot2_(whh[4 * k + 1], hv.y, ah);
      ah = fdot2_(whh[4 * k + 2], hv.z, ah);
      ah = fdot2_(whh[4 * k + 3], hv.w, ah);
    }
    if (j < 64) x16[j] = xv;
    __syncthreads();  // B1: x16 ready
    float ax = bc;
#pragma unroll
    for (int k = 0; k < 16; ++k) {
      uint4 xq = *(const uint4*)&x16[4 * k];
      ax = fdot2_(wih[4 * k + 0], xq.x, ax);
      ax = fdot2_(wih[4 * k + 1], xq.y, ax);
      ax = fdot2_(wih[4 * k + 2], xq.z, ax);
      ax = fdot2_(wih[4 * k + 3], xq.w, ax);
    }
    float g = ax + ah;
    float a = (j >= 256 && j < 384) ? tanh_(g) : sigm_(g);  // rows: i|f|g~|o
    act[j] = a;
    __syncthreads();  // B2: activations ready
    if (j < 64) {
      float2 ia = *(const float2*)&act[2 * j];
      float2 fa = *(const float2*)&act[2 * j + 128];
      float2 ga = *(const float2*)&act[2 * j + 256];
      float2 oa = *(const float2*)&act[2 * j + 384];
      c0 = fa.x * c0 + ia.x * ga.x;
      c1 = fa.y * c1 + ia.y * ga.y;
      float h0 = oa.x * tanh_(c0);
      float h1 = oa.y * tanh_(c1);
      uint32 u = (uint32)f2h_(h0) | ((uint32)f2h_(h1) << 16);
      h16[j] = u;
      if (z < 2) {
        astore_(&hand32[(size_t)z * hstride + (size_t)t * 64 + j], u);
        asm volatile("s_waitcnt vmcnt(0)" ::: "memory");
        if (j == 0) astore_(&flags[z], (uint32)(t + 1));
      } else if (t >= NSTEP - 64) {
        float2 st; st.x = h0; st.y = h1;
        *(float2*)&outs64[(size_t)(t - (NSTEP - 64)) * 128 + 2 * j] = st;
      }
    }
    __syncthreads();  // B3: h16 ready for next step
  }
}

// ---------------- head: relu(fc1) -> sigmoid(fc2) on last 64 rows ----------------
__global__ __launch_bounds__(128) void head_kernel(
    const float* __restrict__ outs64,
    const float* __restrict__ Wfc1, const float* __restrict__ bfc1,
    const float* __restrict__ Wfc2, const float* __restrict__ bfc2,
    float* __restrict__ out) {
  int j = threadIdx.x;
  __shared__ __align__(16) float hbuf[128];
  __shared__ float red[2];
  for (int b = 0; b < 64; ++b) {
    hbuf[j] = outs64[(size_t)b * 128 + j];
    __syncthreads();
    float acc = bfc1[j];
    for (int i = 0; i < 128; i += 4) {
      float4 w4 = *(const float4*)&Wfc1[j * 128 + i];
      float4 h4 = *(const float4*)&hbuf[i];
      acc += w4.x * h4.x + w4.y * h4.y + w4.z * h4.z + w4.w * h4.w;
    }
    float zz = fmaxf(acc, 0.0f) * Wfc2[j];
#pragma unroll
    for (int off = 32; off >= 1; off >>= 1) zz += __shfl_down(zz, off);
    if ((j & 63) == 0) red[j >> 6] = zz;
    __syncthreads();
    if (j == 0) out[b] = rcp_(1.0f + __expf(-(red[0] + red[1] + bfc2[0])));
    __syncthreads();
  }
}

// ---------------- launch ----------------
extern "C" void kernel_launch(void* const* d_in, const int* in_sizes, int n_in,
                              void* d_out, int out_size, void* d_ws, size_t ws_size,
                              hipStream_t stream) {
  const float* sp_emo = (const float*)d_in[0];
  const float* ls_emo = (const float*)d_in[1];
  const float* sp_dmm = (const float*)d_in[2];
  const float* ls_dmm = (const float*)d_in[3];
  const float* pf = (const float*)d_in[4];
  const float* W_em = (const float*)d_in[6];  const float* b_em = (const float*)d_in[7];
  const float* W_3d = (const float*)d_in[8];  const float* b_3d = (const float*)d_in[9];
  const float* Wq_e = (const float*)d_in[10]; const float* bq_e = (const float*)d_in[11];
  const float* Wk_e = (const float*)d_in[12]; const float* bk_e = (const float*)d_in[13];
  const float* Wv_e = (const float*)d_in[14]; const float* bv_e = (const float*)d_in[15];
  const float* Wq_d = (const float*)d_in[16]; const float* bq_d = (const float*)d_in[17];
  const float* Wk_d = (const float*)d_in[18]; const float* bk_d = (const float*)d_in[19];
  const float* Wv_d = (const float*)d_in[20]; const float* bv_d = (const float*)d_in[21];
  const float* W_fus = (const float*)d_in[22]; const float* b_fus = (const float*)d_in[23];
  const float* W_fc1 = (const float*)d_in[24]; const float* b_fc1 = (const float*)d_in[25];
  const float* W_fc2 = (const float*)d_in[26]; const float* b_fc2 = (const float*)d_in[27];
  const float* W_ih = (const float*)d_in[28]; const float* W_hh = (const float*)d_in[29];
  const float* b_ih = (const float*)d_in[30]; const float* b_hh = (const float*)d_in[31];

  char* ws = (char*)d_ws;
  // Region reuse (lifetimes are stream-ordered):
  //  [0, 16809984)        : K buffer (encoder)  -> LSTM handoff slots (2 x 32768 x 64 dwords = 16.78MB)
  //  [16809984, 33619968) : V buffer (encoder)  -> flat16 time-major fp16 enc (8.39MB)
  const size_t o_kvK = 0;
  const size_t o_kvV = 16809984;
  const size_t o_fe = 33619968;
  const size_t o_fd = 50397184;
  const size_t o_wih = 67174400;
  const size_t o_whh = 67567616;
  const size_t o_flag = 67960832;
  const size_t o_outs = 67961088;

  float* Kbuf = (float*)(ws + o_kvK);
  float* Vbuf = (float*)(ws + o_kvV);
  float* febuf = (float*)(ws + o_fe);
  float* fdbuf = (float*)(ws + o_fd);
  uint16* flatbuf = (uint16*)(ws + o_kvV);
  uint32* wih16 = (uint32*)(ws + o_wih);
  uint32* whh16 = (uint32*)(ws + o_whh);
  uint32* flags = (uint32*)(ws + o_flag);
  float* outs64 = (float*)(ws + o_outs);
  uint32* hand32 = (uint32*)(ws + o_kvK);

  prep_kernel<<<3072, 64, 0, stream>>>(W_ih, W_hh, wih16, whh16, flags);
  kv_proj_kernel<<<dim3(9, 64), 256, 0, stream>>>(sp_emo, pf, W_em, b_em, Wk_e, bk_e, Wv_e, bv_e, Kbuf, Vbuf, 25);
  attn_kernel<<<dim3(8, 64), 256, 0, stream>>>(ls_emo, W_em, b_em, Wq_e, bq_e, Kbuf, Vbuf, febuf, 25);
  kv_proj_kernel<<<dim3(9, 64), 256, 0, stream>>>(sp_dmm, pf, W_3d, b_3d, Wk_d, bk_d, Wv_d, bv_d, Kbuf, Vbuf, 58);
  attn_kernel<<<dim3(8, 64), 256, 0, stream>>>(ls_dmm, W_3d, b_3d, Wq_d, bq_d, Kbuf, Vbuf, fdbuf, 58);
  fuse_kernel<<<dim3(8, 64), 256, 0, stream>>>(febuf, fdbuf, W_fus, b_fus, flatbuf);
  lstm_kernel<<<3, 512, 0, stream>>>(wih16, whh16, b_ih, b_hh, (const uint32*)flatbuf, hand32, flags, outs64);
  head_kernel<<<1, 128, 0, stream>>>(outs64, W_fc1, b_fc1, W_fc2, b_fc2, (float*)d_out);
}

// Round 5
// 41182.190 us; speedup vs baseline: 1.4001x; 1.4001x over previous
//
#include <hip/hip_runtime.h>

typedef unsigned int uint32;
typedef unsigned short uint16;

#define NSTEP 32768

// ---------------- helpers ----------------
__device__ __forceinline__ float rcp_(float x) {
#if __has_builtin(__builtin_amdgcn_rcpf)
  return __builtin_amdgcn_rcpf(x);
#else
  return 1.0f / x;
#endif
}
__device__ __forceinline__ float sigm_(float x) { return rcp_(1.0f + __expf(-x)); }
__device__ __forceinline__ float tanh_(float x) { return 1.0f - 2.0f * rcp_(1.0f + __expf(2.0f * x)); }

__device__ __forceinline__ float fdot2_(uint32 a, uint32 b, float c) {
#if __has_builtin(__builtin_amdgcn_fdot2)
  typedef _Float16 h2_t __attribute__((ext_vector_type(2)));
  return __builtin_amdgcn_fdot2(__builtin_bit_cast(h2_t, a), __builtin_bit_cast(h2_t, b), c, false);
#else
  float r;
  asm("v_dot2_f32_f16 %0, %1, %2, %3" : "=v"(r) : "v"(a), "v"(b), "v"(c));
  return r;
#endif
}
__device__ __forceinline__ uint16 f2h_(float x) { return __builtin_bit_cast(uint16, (_Float16)x); }

__device__ __forceinline__ uint32 aload_(uint32* p) {
  return __hip_atomic_load(p, __ATOMIC_RELAXED, __HIP_MEMORY_SCOPE_AGENT);
}
__device__ __forceinline__ uint32 aloadacq_(uint32* p) {
  return __hip_atomic_load(p, __ATOMIC_ACQUIRE, __HIP_MEMORY_SCOPE_AGENT);
}
__device__ __forceinline__ void astore_(uint32* p, uint32 v) {
  __hip_atomic_store(p, v, __ATOMIC_RELAXED, __HIP_MEMORY_SCOPE_AGENT);
}
__device__ __forceinline__ void astorerel_(uint32* p, uint32 v) {
  __hip_atomic_store(p, v, __ATOMIC_RELEASE, __HIP_MEMORY_SCOPE_AGENT);
}

// cross-lane adds: xor1 / xor2 via DPP quad_perm (VALU), xor16 via ds_swizzle
__device__ __forceinline__ float addx1_(float x) {
  int y = __builtin_amdgcn_update_dpp(0, __builtin_bit_cast(int, x), 0xB1, 0xF, 0xF, true);
  return x + __builtin_bit_cast(float, y);
}
__device__ __forceinline__ float addx2_(float x) {
  int y = __builtin_amdgcn_update_dpp(0, __builtin_bit_cast(int, x), 0x4E, 0xF, 0xF, true);
  return x + __builtin_bit_cast(float, y);
}
__device__ __forceinline__ float addx16_(float x) {
  int y = __builtin_amdgcn_ds_swizzle(__builtin_bit_cast(int, x), 0x401F);
  return x + __builtin_bit_cast(float, y);
}

// ---------------- prep: fp16-pack LSTM weights + zero flags ----------------
__global__ __launch_bounds__(64) void prep_kernel(const float* __restrict__ Wih,
                                                  const float* __restrict__ Whh,
                                                  uint32* __restrict__ wih16,
                                                  uint32* __restrict__ whh16,
                                                  uint32* __restrict__ flags) {
  int rg = blockIdx.x;   // 0..3071 (1536 ih rows, 1536 hh rows)
  int d = threadIdx.x;   // 0..63
  const float* src = (rg < 1536) ? Wih : Whh;
  uint32* dst = (rg < 1536) ? wih16 : whh16;
  int row = (rg < 1536) ? rg : rg - 1536;
  float a = src[row * 128 + 2 * d];
  float b = src[row * 128 + 2 * d + 1];
  dst[row * 64 + d] = (uint32)f2h_(a) | ((uint32)f2h_(b) << 16);
  if (rg == 0 && d < 4) flags[d] = 0;
}

// ---------------- K/V projection (incl. pf row 0) ----------------
__global__ __launch_bounds__(256) void kv_proj_kernel(
    const float* __restrict__ src, const float* __restrict__ pf,
    const float* __restrict__ Wemb, const float* __restrict__ bemb,
    const float* __restrict__ Wk, const float* __restrict__ bk,
    const float* __restrict__ Wv, const float* __restrict__ bv,
    float* __restrict__ K, float* __restrict__ V, int in_d) {
  int b = blockIdx.y;
  int s0 = blockIdx.x * 57;
  int tid = threadIdx.x;
  int bsrc = b >> 2;  // jnp.repeat(..., 4, axis=0)
  __shared__ __align__(16) float e_tile[57][128];
  __shared__ __align__(16) float s_tile[57][60];
  int nsrc = 57 * in_d;
  for (int idx = tid; idx < nsrc; idx += 256) {
    int r = idx / in_d, i = idx - r * in_d;
    int s = s0 + r;
    s_tile[r][i] = (s >= 1) ? src[((size_t)bsrc * 512 + (s - 1)) * in_d + i] : 0.0f;
  }
  __syncthreads();
  int j = tid & 127, half = tid >> 7;
  int r0 = half ? 28 : 0;
  {
    float acc[29];
    float bb = bemb[j];
#pragma unroll
    for (int r = 0; r < 29; ++r) acc[r] = bb;
    for (int i = 0; i < in_d; ++i) {
      float w = Wemb[j * in_d + i];
#pragma unroll
      for (int r = 0; r < 29; ++r) acc[r] += w * s_tile[r0 + r][i];
    }
#pragma unroll
    for (int r = 0; r < 29; ++r) {
      int s = s0 + r0 + r;
      e_tile[r0 + r][j] = (s == 0) ? (1e-5f * pf[(size_t)bsrc * 128 + j]) : acc[r];
    }
  }
  __syncthreads();
  {
    float acck[29], accv[29];
    float bkj = bk[j], bvj = bv[j];
#pragma unroll
    for (int r = 0; r < 29; ++r) { acck[r] = bkj; accv[r] = bvj; }
    for (int i = 0; i < 128; i += 4) {
      float4 wk = *(const float4*)&Wk[j * 128 + i];
      float4 wv = *(const float4*)&Wv[j * 128 + i];
#pragma unroll
      for (int r = 0; r < 29; ++r) {
        float4 e4 = *(const float4*)&e_tile[r0 + r][i];
        acck[r] += wk.x * e4.x + wk.y * e4.y + wk.z * e4.z + wk.w * e4.w;
        accv[r] += wv.x * e4.x + wv.y * e4.y + wv.z * e4.z + wv.w * e4.w;
      }
    }
#pragma unroll
    for (int r = 0; r < 29; ++r) {
      int s = s0 + r0 + r;
      K[((size_t)b * 513 + s) * 128 + j] = acck[r];
      V[((size_t)b * 513 + s) * 128 + j] = accv[r];
    }
  }
}

// ---------------- fused flash attention (fp32), q projected on the fly ----------------
__global__ __launch_bounds__(256) void attn_kernel(
    const float* __restrict__ lst,
    const float* __restrict__ Wemb, const float* __restrict__ bemb,
    const float* __restrict__ Wq, const float* __restrict__ bq,
    const float* __restrict__ Kg, const float* __restrict__ Vg,
    float* __restrict__ feat, int in_d) {
  int b = blockIdx.y, qt = blockIdx.x;
  int tid = threadIdx.x;
  __shared__ __align__(16) float q_tile[64][132];
  __shared__ __align__(16) float k_tile[60][132];
  __shared__ __align__(16) float v_tile[60][132];
  __shared__ __align__(16) float p_tile[64][60];
  int nsrc = 64 * in_d;
  for (int idx = tid; idx < nsrc; idx += 256) {
    int r = idx / in_d, i = idx - r * in_d;
    p_tile[r][i] = lst[((size_t)b * 512 + qt * 64 + r) * in_d + i];
  }
  __syncthreads();
  int j = tid & 127, half = tid >> 7;
  int r0 = half * 32;
  {
    float acc[32];
    float bb = bemb[j];
#pragma unroll
    for (int r = 0; r < 32; ++r) acc[r] = bb;
    for (int i = 0; i < in_d; ++i) {
      float w = Wemb[j * in_d + i];
#pragma unroll
      for (int r = 0; r < 32; ++r) acc[r] += w * p_tile[r0 + r][i];
    }
#pragma unroll
    for (int r = 0; r < 32; ++r) k_tile[r0 + r][j] = acc[r];
  }
  __syncthreads();
  {
    float acc[32];
    float bb = bq[j];
#pragma unroll
    for (int r = 0; r < 32; ++r) acc[r] = bb;
    for (int i = 0; i < 128; i += 4) {
      float4 w4 = *(const float4*)&Wq[j * 128 + i];
#pragma unroll
      for (int r = 0; r < 32; ++r) {
        float4 e4 = *(const float4*)&k_tile[r0 + r][i];
        acc[r] += w4.x * e4.x + w4.y * e4.y + w4.z * e4.z + w4.w * e4.w;
      }
    }
#pragma unroll
    for (int r = 0; r < 32; ++r) q_tile[r0 + r][j] = acc[r];
  }
  int r = tid >> 2, c4 = tid & 3;
  float m = -1e30f, l = 0.0f;
  float o[8][4];
#pragma unroll
  for (int kk = 0; kk < 8; ++kk)
#pragma unroll
    for (int x = 0; x < 4; ++x) o[kk][x] = 0.0f;
  const float SCALE = 0.08838834764831845f;
  for (int kt = 0; kt < 9; ++kt) {
    __syncthreads();
    for (int idx = tid; idx < 57 * 32; idx += 256) {
      int rr = idx >> 5, cc = idx & 31;
      *(float4*)&k_tile[rr][cc * 4] = *(const float4*)&Kg[((size_t)b * 513 + kt * 57 + rr) * 128 + cc * 4];
      *(float4*)&v_tile[rr][cc * 4] = *(const float4*)&Vg[((size_t)b * 513 + kt * 57 + rr) * 128 + cc * 4];
    }
    __syncthreads();
    float s[15];
#pragma unroll
    for (int jj = 0; jj < 15; ++jj) s[jj] = 0.0f;
    for (int i = 0; i < 128; i += 4) {
      float4 q4 = *(const float4*)&q_tile[r][i];
#pragma unroll
      for (int jj = 0; jj < 15; ++jj) {
        float4 k4 = *(const float4*)&k_tile[c4 + jj * 4][i];
        s[jj] += q4.x * k4.x + q4.y * k4.y + q4.z * k4.z + q4.w * k4.w;
      }
    }
    float tmax = -1e30f;
#pragma unroll
    for (int jj = 0; jj < 15; ++jj) {
      int jcol = c4 + jj * 4;
      s[jj] = (jcol < 57) ? s[jj] * SCALE : -1e30f;
      tmax = fmaxf(tmax, s[jj]);
    }
    tmax = fmaxf(tmax, __shfl_xor(tmax, 1));
    tmax = fmaxf(tmax, __shfl_xor(tmax, 2));
    float mnew = fmaxf(m, tmax);
    float corr = __expf(m - mnew);
    float psum = 0.0f;
#pragma unroll
    for (int jj = 0; jj < 15; ++jj) {
      float p = __expf(s[jj] - mnew);
      psum += p;
      p_tile[r][c4 + jj * 4] = p;
    }
    psum += __shfl_xor(psum, 1);
    psum += __shfl_xor(psum, 2);
    l = l * corr + psum;
    m = mnew;
#pragma unroll
    for (int kk = 0; kk < 8; ++kk)
#pragma unroll
      for (int x = 0; x < 4; ++x) o[kk][x] *= corr;
    __syncthreads();
    for (int jcol = 0; jcol < 57; ++jcol) {
      float p = p_tile[r][jcol];
#pragma unroll
      for (int kk = 0; kk < 8; ++kk) {
        float4 v4 = *(const float4*)&v_tile[jcol][c4 * 4 + kk * 16];
        o[kk][0] += p * v4.x; o[kk][1] += p * v4.y; o[kk][2] += p * v4.z; o[kk][3] += p * v4.w;
      }
    }
  }
  float rl = 1.0f / l;
#pragma unroll
  for (int kk = 0; kk < 8; ++kk) {
    float4 st;
    st.x = o[kk][0] * rl; st.y = o[kk][1] * rl; st.z = o[kk][2] * rl; st.w = o[kk][3] * rl;
    *(float4*)&feat[((size_t)b * 512 + qt * 64 + r) * 128 + c4 * 4 + kk * 16] = st;
  }
}

// ---------------- fusion: enc = [fe,fd]@Wfus.T+b, written time-major as fp16 ----------------
__global__ __launch_bounds__(256) void fuse_kernel(
    const float* __restrict__ fe, const float* __restrict__ fd,
    const float* __restrict__ Wfus, const float* __restrict__ bfus,
    uint16* __restrict__ flat16) {
  int b = blockIdx.y, tt = blockIdx.x;
  int tid = threadIdx.x;
  __shared__ __align__(16) float f_tile[64][260];
  for (int idx = tid; idx < 64 * 32; idx += 256) {
    int r = idx >> 5, c = idx & 31;
    *(float4*)&f_tile[r][c * 4] = *(const float4*)&fe[((size_t)b * 512 + tt * 64 + r) * 128 + c * 4];
    *(float4*)&f_tile[r][128 + c * 4] = *(const float4*)&fd[((size_t)b * 512 + tt * 64 + r) * 128 + c * 4];
  }
  __syncthreads();
  int j = tid & 127, half = tid >> 7;
  int r0 = half * 32;
  float acc[32];
  float bb = bfus[j];
#pragma unroll
  for (int r = 0; r < 32; ++r) acc[r] = bb;
  for (int i = 0; i < 256; i += 4) {
    float4 w4 = *(const float4*)&Wfus[j * 256 + i];
#pragma unroll
    for (int r = 0; r < 32; ++r) {
      float4 e4 = *(const float4*)&f_tile[r0 + r][i];
      acc[r] += w4.x * e4.x + w4.y * e4.y + w4.z * e4.z + w4.w * e4.w;
    }
  }
#pragma unroll
  for (int r = 0; r < 32; ++r) {
    int t = tt * 64 + r0 + r;
    flat16[((size_t)t * 64 + b) * 128 + j] = f2h_(acc[r]);
  }
}

// ---------------- persistent pipelined LSTM: 3 blocks = 3 layers ----------------
// Partial-sum layout: lane L -> (rr,kk), kk over lane bits {0,1,4}, rr over {2,3,5}.
// Lane owns 8 gate rows (R = 64w + 8rr + a) x one 16-unit k-slice (words 8kk..8kk+7).
// h: 2 ds_read_b128/wave; x: global dwordx4 prefetch (never LDS). Row sums finished by
// allreduce (DPP xor1/xor2 + ds_swizzle xor16) + 7-cndmask select of acc[kk].
__global__ __launch_bounds__(512, 2) void lstm_kernel(
    const uint32* __restrict__ wih16, const uint32* __restrict__ whh16,
    const float* __restrict__ bih, const float* __restrict__ bhh,
    const uint32* __restrict__ flat16,
    uint32* hand32, uint32* flags,
    float* __restrict__ outs64) {
  const int z = blockIdx.x;
  const int j = threadIdx.x;
  const int L = j & 63, w = j >> 6;
  const int kk = (L & 3) | ((L >> 2) & 4);           // lane bits 0,1,4
  const int rr = ((L >> 2) & 3) | (((L >> 5) & 1) << 2);  // lane bits 2,3,5
  const bool kb0 = (L & 1) != 0, kb1 = (L & 2) != 0, kb2 = (L & 16) != 0;
  __shared__ __align__(16) uint32 h16[64];
  __shared__ __align__(16) float act[512];
  uint4 wih[16], whh[16];
#pragma unroll
  for (int a = 0; a < 8; ++a) {
    int R = (w << 6) + (rr << 3) + a;
    const uint32* p = &wih16[((size_t)z * 512 + R) * 64 + (kk << 3)];
    wih[2 * a] = *(const uint4*)p;
    wih[2 * a + 1] = *(const uint4*)(p + 4);
    const uint32* q = &whh16[((size_t)z * 512 + R) * 64 + (kk << 3)];
    whh[2 * a] = *(const uint4*)q;
    whh[2 * a + 1] = *(const uint4*)(q + 4);
  }
  const int myrow = (w << 6) + (rr << 3) + kk;
  const float bcv = bih[(size_t)z * 512 + myrow] + bhh[(size_t)z * 512 + myrow];
  float c0 = 0.0f, c1 = 0.0f;  // wave0 lane j owns hidden units 2j, 2j+1
  if (j < 64) h16[j] = 0;
  __syncthreads();
  const size_t HSTR = (size_t)(NSTEP + 8) * 64;
  const uint32* xsrc = (z == 0) ? flat16 : hand32 + (size_t)(z - 1) * HSTR;
  uint32* hdst = hand32 + (size_t)z * HSTR;
  uint32* flagA = (z > 0) ? &flags[z - 1] : (uint32*)0;
  uint32 Fc = 0;
  // prologue: x(0) + ih-dots(0)
  if (z > 0) { while (Fc < 1u) Fc = aloadacq_(flagA); }
  uint4 xa = *(const uint4*)(xsrc + (kk << 3));
  uint4 xb = *(const uint4*)(xsrc + (kk << 3) + 4);
  float acc[8];
#pragma unroll
  for (int a = 0; a < 8; ++a) {
    float v = 0.0f;
    v = fdot2_(wih[2 * a].x, xa.x, v); v = fdot2_(wih[2 * a].y, xa.y, v);
    v = fdot2_(wih[2 * a].z, xa.z, v); v = fdot2_(wih[2 * a].w, xa.w, v);
    v = fdot2_(wih[2 * a + 1].x, xb.x, v); v = fdot2_(wih[2 * a + 1].y, xb.y, v);
    v = fdot2_(wih[2 * a + 1].z, xb.z, v); v = fdot2_(wih[2 * a + 1].w, xb.w, v);
    acc[a] = v;
  }
  for (int t = 0; t < NSTEP; ++t) {
    // poll flag (batched every 8 by producer) + issue x(t+1) loads (pad-safe at t=NSTEP-1)
    if (z > 0 && t + 2 <= NSTEP) {
      while (Fc < (uint32)(t + 2)) Fc = aloadacq_(flagA);
    }
    const uint32* xp = xsrc + (size_t)(t + 1) * 64 + (kk << 3);
    xa = *(const uint4*)xp;
    xb = *(const uint4*)(xp + 4);
    // hh-dots into acc (h16 = h(t-1), stable since previous B3)
    {
      uint4 ha = *(const uint4*)&h16[kk << 3];
      uint4 hb = *(const uint4*)&h16[(kk << 3) + 4];
#pragma unroll
      for (int a = 0; a < 8; ++a) {
        float v = acc[a];
        v = fdot2_(whh[2 * a].x, ha.x, v); v = fdot2_(whh[2 * a].y, ha.y, v);
        v = fdot2_(whh[2 * a].z, ha.z, v); v = fdot2_(whh[2 * a].w, ha.w, v);
        v = fdot2_(whh[2 * a + 1].x, hb.x, v); v = fdot2_(whh[2 * a + 1].y, hb.y, v);
        v = fdot2_(whh[2 * a + 1].z, hb.z, v); v = fdot2_(whh[2 * a + 1].w, hb.w, v);
        acc[a] = v;
      }
    }
    // allreduce over the kk-group (bits 0,1,4)
#pragma unroll
    for (int a = 0; a < 8; ++a) acc[a] = addx1_(acc[a]);
#pragma unroll
    for (int a = 0; a < 8; ++a) acc[a] = addx2_(acc[a]);
#pragma unroll
    for (int a = 0; a < 8; ++a) acc[a] = addx16_(acc[a]);
    // select acc[kk] (constant-index cndmask tree)
    float s01 = kb0 ? acc[1] : acc[0];
    float s23 = kb0 ? acc[3] : acc[2];
    float s45 = kb0 ? acc[5] : acc[4];
    float s67 = kb0 ? acc[7] : acc[6];
    float s0123 = kb1 ? s23 : s01;
    float s4567 = kb1 ? s67 : s45;
    float g = (kb2 ? s4567 : s0123) + bcv;
    float av = (w == 4 || w == 5) ? tanh_(g) : sigm_(g);  // rows 256..383 = g~
    act[(w << 6) + (rr << 3) + kk] = av;
    __syncthreads();  // B2: activations ready
    if (j < 64) {     // wave 0: h/c update + publish
      float2 ia = *(const float2*)&act[2 * j];
      float2 fa = *(const float2*)&act[2 * j + 128];
      float2 ga = *(const float2*)&act[2 * j + 256];
      float2 oa = *(const float2*)&act[2 * j + 384];
      c0 = fa.x * c0 + ia.x * ga.x;
      c1 = fa.y * c1 + ia.y * ga.y;
      float h0 = oa.x * tanh_(c0);
      float h1 = oa.y * tanh_(c1);
      uint32 u = (uint32)f2h_(h0) | ((uint32)f2h_(h1) << 16);
      h16[j] = u;
      if (z < 2) {
        astore_(&hdst[(size_t)t * 64 + j], u);
        if ((t & 7) == 7) {
          asm volatile("s_waitcnt vmcnt(0)" ::: "memory");
          if (j == 0) astorerel_(&flags[z], (uint32)(t + 1));
        }
      } else if (t >= NSTEP - 64) {
        float2 st; st.x = h0; st.y = h1;
        *(float2*)&outs64[(size_t)(t - (NSTEP - 64)) * 128 + 2 * j] = st;
      }
    }
    // ih-dots for t+1 (overlaps wave0 tail; result discarded on final iteration)
#pragma unroll
    for (int a = 0; a < 8; ++a) {
      float v = 0.0f;
      v = fdot2_(wih[2 * a].x, xa.x, v); v = fdot2_(wih[2 * a].y, xa.y, v);
      v = fdot2_(wih[2 * a].z, xa.z, v); v = fdot2_(wih[2 * a].w, xa.w, v);
      v = fdot2_(wih[2 * a + 1].x, xb.x, v); v = fdot2_(wih[2 * a + 1].y, xb.y, v);
      v = fdot2_(wih[2 * a + 1].z, xb.z, v); v = fdot2_(wih[2 * a + 1].w, xb.w, v);
      acc[a] = v;
    }
    __syncthreads();  // B3: h16(t) ready for next step
  }
}

// ---------------- head: relu(fc1) -> sigmoid(fc2) on last 64 rows ----------------
__global__ __launch_bounds__(128) void head_kernel(
    const float* __restrict__ outs64,
    const float* __restrict__ Wfc1, const float* __restrict__ bfc1,
    const float* __restrict__ Wfc2, const float* __restrict__ bfc2,
    float* __restrict__ out) {
  int j = threadIdx.x;
  __shared__ __align__(16) float hbuf[128];
  __shared__ float red[2];
  for (int b = 0; b < 64; ++b) {
    hbuf[j] = outs64[(size_t)b * 128 + j];
    __syncthreads();
    float acc = bfc1[j];
    for (int i = 0; i < 128; i += 4) {
      float4 w4 = *(const float4*)&Wfc1[j * 128 + i];
      float4 h4 = *(const float4*)&hbuf[i];
      acc += w4.x * h4.x + w4.y * h4.y + w4.z * h4.z + w4.w * h4.w;
    }
    float zz = fmaxf(acc, 0.0f) * Wfc2[j];
#pragma unroll
    for (int off = 32; off >= 1; off >>= 1) zz += __shfl_down(zz, off);
    if ((j & 63) == 0) red[j >> 6] = zz;
    __syncthreads();
    if (j == 0) out[b] = rcp_(1.0f + __expf(-(red[0] + red[1] + bfc2[0])));
    __syncthreads();
  }
}

// ---------------- launch ----------------
extern "C" void kernel_launch(void* const* d_in, const int* in_sizes, int n_in,
                              void* d_out, int out_size, void* d_ws, size_t ws_size,
                              hipStream_t stream) {
  const float* sp_emo = (const float*)d_in[0];
  const float* ls_emo = (const float*)d_in[1];
  const float* sp_dmm = (const float*)d_in[2];
  const float* ls_dmm = (const float*)d_in[3];
  const float* pf = (const float*)d_in[4];
  const float* W_em = (const float*)d_in[6];  const float* b_em = (const float*)d_in[7];
  const float* W_3d = (const float*)d_in[8];  const float* b_3d = (const float*)d_in[9];
  const float* Wq_e = (const float*)d_in[10]; const float* bq_e = (const float*)d_in[11];
  const float* Wk_e = (const float*)d_in[12]; const float* bk_e = (const float*)d_in[13];
  const float* Wv_e = (const float*)d_in[14]; const float* bv_e = (const float*)d_in[15];
  const float* Wq_d = (const float*)d_in[16]; const float* bq_d = (const float*)d_in[17];
  const float* Wk_d = (const float*)d_in[18]; const float* bk_d = (const float*)d_in[19];
  const float* Wv_d = (const float*)d_in[20]; const float* bv_d = (const float*)d_in[21];
  const float* W_fus = (const float*)d_in[22]; const float* b_fus = (const float*)d_in[23];
  const float* W_fc1 = (const float*)d_in[24]; const float* b_fc1 = (const float*)d_in[25];
  const float* W_fc2 = (const float*)d_in[26]; const float* b_fc2 = (const float*)d_in[27];
  const float* W_ih = (const float*)d_in[28]; const float* W_hh = (const float*)d_in[29];
  const float* b_ih = (const float*)d_in[30]; const float* b_hh = (const float*)d_in[31];

  char* ws = (char*)d_ws;
  // Region reuse (stream-ordered lifetimes):
  //  [0, 16809984)        : K buffer (encoder)  -> LSTM handoff (2 layers x (NSTEP+8)*64 dwords = 16.78MB)
  //  [16809984, 33619968) : V buffer (encoder)  -> flat16 time-major fp16 enc (8.39MB + pad)
  const size_t o_kvK = 0;
  const size_t o_kvV = 16809984;
  const size_t o_fe = 33619968;
  const size_t o_fd = 50397184;
  const size_t o_wih = 67174400;
  const size_t o_whh = 67567616;
  const size_t o_flag = 67960832;
  const size_t o_outs = 67961088;

  float* Kbuf = (float*)(ws + o_kvK);
  float* Vbuf = (float*)(ws + o_kvV);
  float* febuf = (float*)(ws + o_fe);
  float* fdbuf = (float*)(ws + o_fd);
  uint16* flatbuf = (uint16*)(ws + o_kvV);
  uint32* wih16 = (uint32*)(ws + o_wih);
  uint32* whh16 = (uint32*)(ws + o_whh);
  uint32* flags = (uint32*)(ws + o_flag);
  float* outs64 = (float*)(ws + o_outs);
  uint32* hand32 = (uint32*)(ws + o_kvK);

  prep_kernel<<<3072, 64, 0, stream>>>(W_ih, W_hh, wih16, whh16, flags);
  kv_proj_kernel<<<dim3(9, 64), 256, 0, stream>>>(sp_emo, pf, W_em, b_em, Wk_e, bk_e, Wv_e, bv_e, Kbuf, Vbuf, 25);
  attn_kernel<<<dim3(8, 64), 256, 0, stream>>>(ls_emo, W_em, b_em, Wq_e, bq_e, Kbuf, Vbuf, febuf, 25);
  kv_proj_kernel<<<dim3(9, 64), 256, 0, stream>>>(sp_dmm, pf, W_3d, b_3d, Wk_d, bk_d, Wv_d, bv_d, Kbuf, Vbuf, 58);
  attn_kernel<<<dim3(8, 64), 256, 0, stream>>>(ls_dmm, W_3d, b_3d, Wq_d, bq_d, Kbuf, Vbuf, fdbuf, 58);
  fuse_kernel<<<dim3(8, 64), 256, 0, stream>>>(febuf, fdbuf, W_fus, b_fus, flatbuf);
  lstm_kernel<<<3, 512, 0, stream>>>(wih16, whh16, b_ih, b_hh, (const uint32*)flatbuf, hand32, flags, outs64);
  head_kernel<<<1, 128, 0, stream>>>(outs64, W_fc1, b_fc1, W_fc2, b_fc2, (float*)d_out);
}

// Round 6
// 36269.891 us; speedup vs baseline: 1.5897x; 1.1354x over previous
//
#include <hip/hip_runtime.h>

typedef unsigned int uint32;
typedef unsigned short uint16;

#define NSTEP 32768

// ---------------- helpers ----------------
__device__ __forceinline__ float rcp_(float x) {
#if __has_builtin(__builtin_amdgcn_rcpf)
  return __builtin_amdgcn_rcpf(x);
#else
  return 1.0f / x;
#endif
}
__device__ __forceinline__ float sigm_(float x) { return rcp_(1.0f + __expf(-x)); }
__device__ __forceinline__ float tanh_(float x) { return 1.0f - 2.0f * rcp_(1.0f + __expf(2.0f * x)); }

__device__ __forceinline__ float fdot2_(uint32 a, uint32 b, float c) {
#if __has_builtin(__builtin_amdgcn_fdot2)
  typedef _Float16 h2_t __attribute__((ext_vector_type(2)));
  return __builtin_amdgcn_fdot2(__builtin_bit_cast(h2_t, a), __builtin_bit_cast(h2_t, b), c, false);
#else
  float r;
  asm("v_dot2_f32_f16 %0, %1, %2, %3" : "=v"(r) : "v"(a), "v"(b), "v"(c));
  return r;
#endif
}
__device__ __forceinline__ uint16 f2h_(float x) { return __builtin_bit_cast(uint16, (_Float16)x); }

__device__ __forceinline__ uint32 aload_(uint32* p) {
  return __hip_atomic_load(p, __ATOMIC_RELAXED, __HIP_MEMORY_SCOPE_AGENT);
}
__device__ __forceinline__ uint32 aloadacq_(uint32* p) {
  return __hip_atomic_load(p, __ATOMIC_ACQUIRE, __HIP_MEMORY_SCOPE_AGENT);
}
__device__ __forceinline__ void astore_(uint32* p, uint32 v) {
  __hip_atomic_store(p, v, __ATOMIC_RELAXED, __HIP_MEMORY_SCOPE_AGENT);
}
__device__ __forceinline__ void astorerel_(uint32* p, uint32 v) {
  __hip_atomic_store(p, v, __ATOMIC_RELEASE, __HIP_MEMORY_SCOPE_AGENT);
}

// cross-lane adds: xor1 / xor2 via DPP quad_perm (VALU), xor16 via ds_swizzle
__device__ __forceinline__ float addx1_(float x) {
  int y = __builtin_amdgcn_update_dpp(0, __builtin_bit_cast(int, x), 0xB1, 0xF, 0xF, true);
  return x + __builtin_bit_cast(float, y);
}
__device__ __forceinline__ float addx2_(float x) {
  int y = __builtin_amdgcn_update_dpp(0, __builtin_bit_cast(int, x), 0x4E, 0xF, 0xF, true);
  return x + __builtin_bit_cast(float, y);
}
__device__ __forceinline__ float addx16_(float x) {
  int y = __builtin_amdgcn_ds_swizzle(__builtin_bit_cast(int, x), 0x401F);
  return x + __builtin_bit_cast(float, y);
}

// ---------------- prep: fp16-pack LSTM weights + zero flags ----------------
__global__ __launch_bounds__(64) void prep_kernel(const float* __restrict__ Wih,
                                                  const float* __restrict__ Whh,
                                                  uint32* __restrict__ wih16,
                                                  uint32* __restrict__ whh16,
                                                  uint32* __restrict__ flags) {
  int rg = blockIdx.x;   // 0..3071 (1536 ih rows, 1536 hh rows)
  int d = threadIdx.x;   // 0..63
  const float* src = (rg < 1536) ? Wih : Whh;
  uint32* dst = (rg < 1536) ? wih16 : whh16;
  int row = (rg < 1536) ? rg : rg - 1536;
  float a = src[row * 128 + 2 * d];
  float b = src[row * 128 + 2 * d + 1];
  dst[row * 64 + d] = (uint32)f2h_(a) | ((uint32)f2h_(b) << 16);
  if (rg == 0 && d < 4) flags[d] = 0;
}

// ---------------- K/V projection (incl. pf row 0) ----------------
__global__ __launch_bounds__(256) void kv_proj_kernel(
    const float* __restrict__ src, const float* __restrict__ pf,
    const float* __restrict__ Wemb, const float* __restrict__ bemb,
    const float* __restrict__ Wk, const float* __restrict__ bk,
    const float* __restrict__ Wv, const float* __restrict__ bv,
    float* __restrict__ K, float* __restrict__ V, int in_d) {
  int b = blockIdx.y;
  int s0 = blockIdx.x * 57;
  int tid = threadIdx.x;
  int bsrc = b >> 2;  // jnp.repeat(..., 4, axis=0)
  __shared__ __align__(16) float e_tile[57][128];
  __shared__ __align__(16) float s_tile[57][60];
  int nsrc = 57 * in_d;
  for (int idx = tid; idx < nsrc; idx += 256) {
    int r = idx / in_d, i = idx - r * in_d;
    int s = s0 + r;
    s_tile[r][i] = (s >= 1) ? src[((size_t)bsrc * 512 + (s - 1)) * in_d + i] : 0.0f;
  }
  __syncthreads();
  int j = tid & 127, half = tid >> 7;
  int r0 = half ? 28 : 0;
  {
    float acc[29];
    float bb = bemb[j];
#pragma unroll
    for (int r = 0; r < 29; ++r) acc[r] = bb;
    for (int i = 0; i < in_d; ++i) {
      float w = Wemb[j * in_d + i];
#pragma unroll
      for (int r = 0; r < 29; ++r) acc[r] += w * s_tile[r0 + r][i];
    }
#pragma unroll
    for (int r = 0; r < 29; ++r) {
      int s = s0 + r0 + r;
      e_tile[r0 + r][j] = (s == 0) ? (1e-5f * pf[(size_t)bsrc * 128 + j]) : acc[r];
    }
  }
  __syncthreads();
  {
    float acck[29], accv[29];
    float bkj = bk[j], bvj = bv[j];
#pragma unroll
    for (int r = 0; r < 29; ++r) { acck[r] = bkj; accv[r] = bvj; }
    for (int i = 0; i < 128; i += 4) {
      float4 wk = *(const float4*)&Wk[j * 128 + i];
      float4 wv = *(const float4*)&Wv[j * 128 + i];
#pragma unroll
      for (int r = 0; r < 29; ++r) {
        float4 e4 = *(const float4*)&e_tile[r0 + r][i];
        acck[r] += wk.x * e4.x + wk.y * e4.y + wk.z * e4.z + wk.w * e4.w;
        accv[r] += wv.x * e4.x + wv.y * e4.y + wv.z * e4.z + wv.w * e4.w;
      }
    }
#pragma unroll
    for (int r = 0; r < 29; ++r) {
      int s = s0 + r0 + r;
      K[((size_t)b * 513 + s) * 128 + j] = acck[r];
      V[((size_t)b * 513 + s) * 128 + j] = accv[r];
    }
  }
}

// ---------------- fused flash attention (fp32), q projected on the fly ----------------
__global__ __launch_bounds__(256) void attn_kernel(
    const float* __restrict__ lst,
    const float* __restrict__ Wemb, const float* __restrict__ bemb,
    const float* __restrict__ Wq, const float* __restrict__ bq,
    const float* __restrict__ Kg, const float* __restrict__ Vg,
    float* __restrict__ feat, int in_d) {
  int b = blockIdx.y, qt = blockIdx.x;
  int tid = threadIdx.x;
  __shared__ __align__(16) float q_tile[64][132];
  __shared__ __align__(16) float k_tile[60][132];
  __shared__ __align__(16) float v_tile[60][132];
  __shared__ __align__(16) float p_tile[64][60];
  int nsrc = 64 * in_d;
  for (int idx = tid; idx < nsrc; idx += 256) {
    int r = idx / in_d, i = idx - r * in_d;
    p_tile[r][i] = lst[((size_t)b * 512 + qt * 64 + r) * in_d + i];
  }
  __syncthreads();
  int j = tid & 127, half = tid >> 7;
  int r0 = half * 32;
  {
    float acc[32];
    float bb = bemb[j];
#pragma unroll
    for (int r = 0; r < 32; ++r) acc[r] = bb;
    for (int i = 0; i < in_d; ++i) {
      float w = Wemb[j * in_d + i];
#pragma unroll
      for (int r = 0; r < 32; ++r) acc[r] += w * p_tile[r0 + r][i];
    }
#pragma unroll
    for (int r = 0; r < 32; ++r) k_tile[r0 + r][j] = acc[r];
  }
  __syncthreads();
  {
    float acc[32];
    float bb = bq[j];
#pragma unroll
    for (int r = 0; r < 32; ++r) acc[r] = bb;
    for (int i = 0; i < 128; i += 4) {
      float4 w4 = *(const float4*)&Wq[j * 128 + i];
#pragma unroll
      for (int r = 0; r < 32; ++r) {
        float4 e4 = *(const float4*)&k_tile[r0 + r][i];
        acc[r] += w4.x * e4.x + w4.y * e4.y + w4.z * e4.z + w4.w * e4.w;
      }
    }
#pragma unroll
    for (int r = 0; r < 32; ++r) q_tile[r0 + r][j] = acc[r];
  }
  int r = tid >> 2, c4 = tid & 3;
  float m = -1e30f, l = 0.0f;
  float o[8][4];
#pragma unroll
  for (int kk = 0; kk < 8; ++kk)
#pragma unroll
    for (int x = 0; x < 4; ++x) o[kk][x] = 0.0f;
  const float SCALE = 0.08838834764831845f;
  for (int kt = 0; kt < 9; ++kt) {
    __syncthreads();
    for (int idx = tid; idx < 57 * 32; idx += 256) {
      int rr = idx >> 5, cc = idx & 31;
      *(float4*)&k_tile[rr][cc * 4] = *(const float4*)&Kg[((size_t)b * 513 + kt * 57 + rr) * 128 + cc * 4];
      *(float4*)&v_tile[rr][cc * 4] = *(const float4*)&Vg[((size_t)b * 513 + kt * 57 + rr) * 128 + cc * 4];
    }
    __syncthreads();
    float s[15];
#pragma unroll
    for (int jj = 0; jj < 15; ++jj) s[jj] = 0.0f;
    for (int i = 0; i < 128; i += 4) {
      float4 q4 = *(const float4*)&q_tile[r][i];
#pragma unroll
      for (int jj = 0; jj < 15; ++jj) {
        float4 k4 = *(const float4*)&k_tile[c4 + jj * 4][i];
        s[jj] += q4.x * k4.x + q4.y * k4.y + q4.z * k4.z + q4.w * k4.w;
      }
    }
    float tmax = -1e30f;
#pragma unroll
    for (int jj = 0; jj < 15; ++jj) {
      int jcol = c4 + jj * 4;
      s[jj] = (jcol < 57) ? s[jj] * SCALE : -1e30f;
      tmax = fmaxf(tmax, s[jj]);
    }
    tmax = fmaxf(tmax, __shfl_xor(tmax, 1));
    tmax = fmaxf(tmax, __shfl_xor(tmax, 2));
    float mnew = fmaxf(m, tmax);
    float corr = __expf(m - mnew);
    float psum = 0.0f;
#pragma unroll
    for (int jj = 0; jj < 15; ++jj) {
      float p = __expf(s[jj] - mnew);
      psum += p;
      p_tile[r][c4 + jj * 4] = p;
    }
    psum += __shfl_xor(psum, 1);
    psum += __shfl_xor(psum, 2);
    l = l * corr + psum;
    m = mnew;
#pragma unroll
    for (int kk = 0; kk < 8; ++kk)
#pragma unroll
      for (int x = 0; x < 4; ++x) o[kk][x] *= corr;
    __syncthreads();
    for (int jcol = 0; jcol < 57; ++jcol) {
      float p = p_tile[r][jcol];
#pragma unroll
      for (int kk = 0; kk < 8; ++kk) {
        float4 v4 = *(const float4*)&v_tile[jcol][c4 * 4 + kk * 16];
        o[kk][0] += p * v4.x; o[kk][1] += p * v4.y; o[kk][2] += p * v4.z; o[kk][3] += p * v4.w;
      }
    }
  }
  float rl = 1.0f / l;
#pragma unroll
  for (int kk = 0; kk < 8; ++kk) {
    float4 st;
    st.x = o[kk][0] * rl; st.y = o[kk][1] * rl; st.z = o[kk][2] * rl; st.w = o[kk][3] * rl;
    *(float4*)&feat[((size_t)b * 512 + qt * 64 + r) * 128 + c4 * 4 + kk * 16] = st;
  }
}

// ---------------- fusion: enc = [fe,fd]@Wfus.T+b, written time-major as fp16 ----------------
__global__ __launch_bounds__(256) void fuse_kernel(
    const float* __restrict__ fe, const float* __restrict__ fd,
    const float* __restrict__ Wfus, const float* __restrict__ bfus,
    uint16* __restrict__ flat16) {
  int b = blockIdx.y, tt = blockIdx.x;
  int tid = threadIdx.x;
  __shared__ __align__(16) float f_tile[64][260];
  for (int idx = tid; idx < 64 * 32; idx += 256) {
    int r = idx >> 5, c = idx & 31;
    *(float4*)&f_tile[r][c * 4] = *(const float4*)&fe[((size_t)b * 512 + tt * 64 + r) * 128 + c * 4];
    *(float4*)&f_tile[r][128 + c * 4] = *(const float4*)&fd[((size_t)b * 512 + tt * 64 + r) * 128 + c * 4];
  }
  __syncthreads();
  int j = tid & 127, half = tid >> 7;
  int r0 = half * 32;
  float acc[32];
  float bb = bfus[j];
#pragma unroll
  for (int r = 0; r < 32; ++r) acc[r] = bb;
  for (int i = 0; i < 256; i += 4) {
    float4 w4 = *(const float4*)&Wfus[j * 256 + i];
#pragma unroll
    for (int r = 0; r < 32; ++r) {
      float4 e4 = *(const float4*)&f_tile[r0 + r][i];
      acc[r] += w4.x * e4.x + w4.y * e4.y + w4.z * e4.z + w4.w * e4.w;
    }
  }
#pragma unroll
  for (int r = 0; r < 32; ++r) {
    int t = tt * 64 + r0 + r;
    flat16[((size_t)t * 64 + b) * 128 + j] = f2h_(acc[r]);
  }
}

// ---------------- persistent pipelined LSTM: 3 blocks = 3 layers ----------------
// v2: (a) weights in 32 NAMED uint4 regs (no arrays -> no SROA spill), launch_bounds(512,1);
//     (b) zero hot-line atomics: lane0-only watermark poll, wave0-only x fetch (sc1 relaxed
//         atomic dwords, issued at step top for t+2) -> double-buffered LDS xbuf.
__global__ __launch_bounds__(512, 1) void lstm_kernel(
    const uint32* __restrict__ wih16, const uint32* __restrict__ whh16,
    const float* __restrict__ bih, const float* __restrict__ bhh,
    const uint32* __restrict__ flat16,
    uint32* hand32, uint32* flags,
    float* __restrict__ outs64) {
  const int z = blockIdx.x;
  const int j = threadIdx.x;
  const int L = j & 63, w = j >> 6;
  const int kk = (L & 3) | ((L >> 2) & 4);                // lane bits 0,1,4
  const int rr = ((L >> 2) & 3) | (((L >> 5) & 1) << 2);  // lane bits 2,3,5
  const bool kb0 = (L & 1) != 0, kb1 = (L & 2) != 0, kb2 = (L & 16) != 0;
  __shared__ __align__(16) uint32 h16[64];
  __shared__ __align__(16) uint32 xbuf[2][64];
  __shared__ __align__(16) float act[512];

#define DECLW(a) uint4 wiA##a, wiB##a, whA##a, whB##a;
  DECLW(0) DECLW(1) DECLW(2) DECLW(3) DECLW(4) DECLW(5) DECLW(6) DECLW(7)
#undef DECLW
#define LOADW(a) { const int R = (w << 6) + (rr << 3) + a; \
    const uint32* p = &wih16[((size_t)z * 512 + R) * 64 + (kk << 3)]; \
    wiA##a = *(const uint4*)p; wiB##a = *(const uint4*)(p + 4); \
    const uint32* q = &whh16[((size_t)z * 512 + R) * 64 + (kk << 3)]; \
    whA##a = *(const uint4*)q; whB##a = *(const uint4*)(q + 4); }
  LOADW(0) LOADW(1) LOADW(2) LOADW(3) LOADW(4) LOADW(5) LOADW(6) LOADW(7)
#undef LOADW
  const int myrow = (w << 6) + (rr << 3) + kk;
  const float bcv = bih[(size_t)z * 512 + myrow] + bhh[(size_t)z * 512 + myrow];
  float c0 = 0.0f, c1 = 0.0f;  // wave0 lane j owns hidden units 2j, 2j+1

  const size_t HSTR = (size_t)(NSTEP + 8) * 64;
  const uint32* xsrc = (z == 0) ? flat16 : hand32 + (size_t)(z - 1) * HSTR;
  uint32* hdst = hand32 + (size_t)z * HSTR;
  uint32* flagA = (z > 0) ? &flags[z - 1] : (uint32*)0;
  uint32 Fc = 0;

  // prologue: x(0) -> xbuf[0], x(1) -> xbuf[1]; needs flag >= 3 (covers issue of x(2) at t=0)
  if (j < 64) {
    if (z > 0 && j == 0) { while (Fc < 3u) Fc = aloadacq_(flagA); }
    uint32 x0, x1;
    if (z == 0) { x0 = xsrc[j]; x1 = xsrc[64 + j]; }
    else { x0 = aload_((uint32*)&xsrc[j]); x1 = aload_((uint32*)&xsrc[64 + j]); }
    xbuf[0][j] = x0; xbuf[1][j] = x1;
    h16[j] = 0;
  }
  __syncthreads();

  float acc0, acc1, acc2, acc3, acc4, acc5, acc6, acc7;
#define IHDOT(a) { float v = 0.0f; \
    v = fdot2_(wiA##a.x, xa.x, v); v = fdot2_(wiA##a.y, xa.y, v); \
    v = fdot2_(wiA##a.z, xa.z, v); v = fdot2_(wiA##a.w, xa.w, v); \
    v = fdot2_(wiB##a.x, xb.x, v); v = fdot2_(wiB##a.y, xb.y, v); \
    v = fdot2_(wiB##a.z, xb.z, v); v = fdot2_(wiB##a.w, xb.w, v); \
    acc##a = v; }
#define HHDOT(a) { float v = acc##a; \
    v = fdot2_(whA##a.x, ha.x, v); v = fdot2_(whA##a.y, ha.y, v); \
    v = fdot2_(whA##a.z, ha.z, v); v = fdot2_(whA##a.w, ha.w, v); \
    v = fdot2_(whB##a.x, hb.x, v); v = fdot2_(whB##a.y, hb.y, v); \
    v = fdot2_(whB##a.z, hb.z, v); v = fdot2_(whB##a.w, hb.w, v); \
    acc##a = v; }
  {  // acc = ih(0) from xbuf[0]
    uint4 xa = *(const uint4*)&xbuf[0][kk << 3];
    uint4 xb = *(const uint4*)&xbuf[0][(kk << 3) + 4];
    IHDOT(0) IHDOT(1) IHDOT(2) IHDOT(3) IHDOT(4) IHDOT(5) IHDOT(6) IHDOT(7)
  }

  for (int t = 0; t < NSTEP; ++t) {
    // wave0: issue x(t+2) (flag >= t+3 guaranteed by last iter's poll; pad region covers tail)
    uint32 xv = 0;
    if (j < 64) {
      const size_t xi = (size_t)(t + 2) * 64 + j;
      xv = (z == 0) ? xsrc[xi] : aload_((uint32*)&xsrc[xi]);
    }
    {  // hh-dots (h16 = h(t-1), stable since prev B3)
      uint4 ha = *(const uint4*)&h16[kk << 3];
      uint4 hb = *(const uint4*)&h16[(kk << 3) + 4];
      HHDOT(0) HHDOT(1) HHDOT(2) HHDOT(3) HHDOT(4) HHDOT(5) HHDOT(6) HHDOT(7)
    }
    // allreduce over kk-group (lane bits 0,1,4)
    acc0 = addx1_(acc0); acc1 = addx1_(acc1); acc2 = addx1_(acc2); acc3 = addx1_(acc3);
    acc4 = addx1_(acc4); acc5 = addx1_(acc5); acc6 = addx1_(acc6); acc7 = addx1_(acc7);
    acc0 = addx2_(acc0); acc1 = addx2_(acc1); acc2 = addx2_(acc2); acc3 = addx2_(acc3);
    acc4 = addx2_(acc4); acc5 = addx2_(acc5); acc6 = addx2_(acc6); acc7 = addx2_(acc7);
    acc0 = addx16_(acc0); acc1 = addx16_(acc1); acc2 = addx16_(acc2); acc3 = addx16_(acc3);
    acc4 = addx16_(acc4); acc5 = addx16_(acc5); acc6 = addx16_(acc6); acc7 = addx16_(acc7);
    float s01 = kb0 ? acc1 : acc0;
    float s23 = kb0 ? acc3 : acc2;
    float s45 = kb0 ? acc5 : acc4;
    float s67 = kb0 ? acc7 : acc6;
    float s0123 = kb1 ? s23 : s01;
    float s4567 = kb1 ? s67 : s45;
    float g = (kb2 ? s4567 : s0123) + bcv;
    float av = (w == 4 || w == 5) ? tanh_(g) : sigm_(g);  // rows 256..383 = g~
    act[myrow] = av;
    __syncthreads();  // B2: activations ready
    if (j < 64) {     // wave0: h/c update + publish + x staging + watermark poll
      float2 ia = *(const float2*)&act[2 * j];
      float2 fa = *(const float2*)&act[2 * j + 128];
      float2 ga = *(const float2*)&act[2 * j + 256];
      float2 oa = *(const float2*)&act[2 * j + 384];
      c0 = fa.x * c0 + ia.x * ga.x;
      c1 = fa.y * c1 + ia.y * ga.y;
      float h0 = oa.x * tanh_(c0);
      float h1 = oa.y * tanh_(c1);
      uint32 u = (uint32)f2h_(h0) | ((uint32)f2h_(h1) << 16);
      h16[j] = u;
      if (z < 2) {
        astore_(&hdst[(size_t)t * 64 + j], u);
        if ((t & 7) == 7) {
          asm volatile("s_waitcnt vmcnt(0)" ::: "memory");
          if (j == 0) astorerel_(&flags[z], (uint32)(t + 1));
        }
      } else if (t >= NSTEP - 64) {
        float2 st; st.x = h0; st.y = h1;
        *(float2*)&outs64[(size_t)(t - (NSTEP - 64)) * 128 + 2 * j] = st;
      }
      xbuf[t & 1][j] = xv;  // x(t+2) -> slot (t+2)&1; read next iter post-B2
      if (z > 0 && j == 0) {  // watermark check: ~1 real atomic load per 8 steps
        const uint32 tgt = (t + 4 <= NSTEP) ? (uint32)(t + 4) : (uint32)NSTEP;
        while (Fc < tgt) Fc = aloadacq_(flagA);
      }
    }
    {  // ih-dots for t+1 from xbuf[(t+1)&1] (stable; written iter t-1, B3 between)
      const uint32* xp = &xbuf[(t + 1) & 1][0];
      uint4 xa = *(const uint4*)&xp[kk << 3];
      uint4 xb = *(const uint4*)&xp[(kk << 3) + 4];
      IHDOT(0) IHDOT(1) IHDOT(2) IHDOT(3) IHDOT(4) IHDOT(5) IHDOT(6) IHDOT(7)
    }
    __syncthreads();  // B3: h16(t) + xbuf ready for next step
  }
#undef IHDOT
#undef HHDOT
}

// ---------------- head: relu(fc1) -> sigmoid(fc2) on last 64 rows ----------------
__global__ __launch_bounds__(128) void head_kernel(
    const float* __restrict__ outs64,
    const float* __restrict__ Wfc1, const float* __restrict__ bfc1,
    const float* __restrict__ Wfc2, const float* __restrict__ bfc2,
    float* __restrict__ out) {
  int j = threadIdx.x;
  __shared__ __align__(16) float hbuf[128];
  __shared__ float red[2];
  for (int b = 0; b < 64; ++b) {
    hbuf[j] = outs64[(size_t)b * 128 + j];
    __syncthreads();
    float acc = bfc1[j];
    for (int i = 0; i < 128; i += 4) {
      float4 w4 = *(const float4*)&Wfc1[j * 128 + i];
      float4 h4 = *(const float4*)&hbuf[i];
      acc += w4.x * h4.x + w4.y * h4.y + w4.z * h4.z + w4.w * h4.w;
    }
    float zz = fmaxf(acc, 0.0f) * Wfc2[j];
#pragma unroll
    for (int off = 32; off >= 1; off >>= 1) zz += __shfl_down(zz, off);
    if ((j & 63) == 0) red[j >> 6] = zz;
    __syncthreads();
    if (j == 0) out[b] = rcp_(1.0f + __expf(-(red[0] + red[1] + bfc2[0])));
    __syncthreads();
  }
}

// ---------------- launch ----------------
extern "C" void kernel_launch(void* const* d_in, const int* in_sizes, int n_in,
                              void* d_out, int out_size, void* d_ws, size_t ws_size,
                              hipStream_t stream) {
  const float* sp_emo = (const float*)d_in[0];
  const float* ls_emo = (const float*)d_in[1];
  const float* sp_dmm = (const float*)d_in[2];
  const float* ls_dmm = (const float*)d_in[3];
  const float* pf = (const float*)d_in[4];
  const float* W_em = (const float*)d_in[6];  const float* b_em = (const float*)d_in[7];
  const float* W_3d = (const float*)d_in[8];  const float* b_3d = (const float*)d_in[9];
  const float* Wq_e = (const float*)d_in[10]; const float* bq_e = (const float*)d_in[11];
  const float* Wk_e = (const float*)d_in[12]; const float* bk_e = (const float*)d_in[13];
  const float* Wv_e = (const float*)d_in[14]; const float* bv_e = (const float*)d_in[15];
  const float* Wq_d = (const float*)d_in[16]; const float* bq_d = (const float*)d_in[17];
  const float* Wk_d = (const float*)d_in[18]; const float* bk_d = (const float*)d_in[19];
  const float* Wv_d = (const float*)d_in[20]; const float* bv_d = (const float*)d_in[21];
  const float* W_fus = (const float*)d_in[22]; const float* b_fus = (const float*)d_in[23];
  const float* W_fc1 = (const float*)d_in[24]; const float* b_fc1 = (const float*)d_in[25];
  const float* W_fc2 = (const float*)d_in[26]; const float* b_fc2 = (const float*)d_in[27];
  const float* W_ih = (const float*)d_in[28]; const float* W_hh = (const float*)d_in[29];
  const float* b_ih = (const float*)d_in[30]; const float* b_hh = (const float*)d_in[31];

  char* ws = (char*)d_ws;
  // Region reuse (stream-ordered lifetimes):
  //  [0, 16809984)        : K buffer (encoder)  -> LSTM handoff (2 layers x (NSTEP+8)*64 dwords)
  //  [16809984, 33619968) : V buffer (encoder)  -> flat16 time-major fp16 enc (8.39MB + pad)
  const size_t o_kvK = 0;
  const size_t o_kvV = 16809984;
  const size_t o_fe = 33619968;
  const size_t o_fd = 50397184;
  const size_t o_wih = 67174400;
  const size_t o_whh = 67567616;
  const size_t o_flag = 67960832;
  const size_t o_outs = 67961088;

  float* Kbuf = (float*)(ws + o_kvK);
  float* Vbuf = (float*)(ws + o_kvV);
  float* febuf = (float*)(ws + o_fe);
  float* fdbuf = (float*)(ws + o_fd);
  uint16* flatbuf = (uint16*)(ws + o_kvV);
  uint32* wih16 = (uint32*)(ws + o_wih);
  uint32* whh16 = (uint32*)(ws + o_whh);
  uint32* flags = (uint32*)(ws + o_flag);
  float* outs64 = (float*)(ws + o_outs);
  uint32* hand32 = (uint32*)(ws + o_kvK);

  prep_kernel<<<3072, 64, 0, stream>>>(W_ih, W_hh, wih16, whh16, flags);
  kv_proj_kernel<<<dim3(9, 64), 256, 0, stream>>>(sp_emo, pf, W_em, b_em, Wk_e, bk_e, Wv_e, bv_e, Kbuf, Vbuf, 25);
  attn_kernel<<<dim3(8, 64), 256, 0, stream>>>(ls_emo, W_em, b_em, Wq_e, bq_e, Kbuf, Vbuf, febuf, 25);
  kv_proj_kernel<<<dim3(9, 64), 256, 0, stream>>>(sp_dmm, pf, W_3d, b_3d, Wk_d, bk_d, Wv_d, bv_d, Kbuf, Vbuf, 58);
  attn_kernel<<<dim3(8, 64), 256, 0, stream>>>(ls_dmm, W_3d, b_3d, Wq_d, bq_d, Kbuf, Vbuf, fdbuf, 58);
  fuse_kernel<<<dim3(8, 64), 256, 0, stream>>>(febuf, fdbuf, W_fus, b_fus, flatbuf);
  lstm_kernel<<<3, 512, 0, stream>>>(wih16, whh16, b_ih, b_hh, (const uint32*)flatbuf, hand32, flags, outs64);
  head_kernel<<<1, 128, 0, stream>>>(outs64, W_fc1, b_fc1, W_fc2, b_fc2, (float*)d_out);
}